// Round 7
// baseline (277.332 us; speedup 1.0000x reference)
//
#include <hip/hip_runtime.h>

#define DIM 128
#define EPB_A 8192    // edges per histscat block
#define BSH 10        // bucket = dst >> 10 (1024 nodes per bucket)
#define BNODES 1024
#define CAPB 18432    // per-bucket slab capacity (mean 16384, +16 sigma)
#define NBMAX 128

// ---------- bf16 helpers ----------
__device__ __forceinline__ float bf_lo(unsigned u) { return __uint_as_float(u << 16); }
__device__ __forceinline__ float bf_hi(unsigned u) { return __uint_as_float(u & 0xffff0000u); }
__device__ __forceinline__ unsigned short f2bf(float f) {
    unsigned u = __float_as_uint(f);
    u += 0x7fff + ((u >> 16) & 1);   // round-to-nearest-even
    return (unsigned short)(u >> 16);
}
__device__ __forceinline__ unsigned packbf(float a, float b) {
    return (unsigned)f2bf(a) | ((unsigned)f2bf(b) << 16);
}

#if __has_builtin(__builtin_amdgcn_fdot2_f32_bf16)
#define HAVE_DOT2 1
typedef __bf16 bf16x2 __attribute__((ext_vector_type(2)));
__device__ __forceinline__ float dot2bf(unsigned ab, unsigned nn, float acc) {
    return __builtin_amdgcn_fdot2_f32_bf16(
        __builtin_bit_cast(bf16x2, ab), __builtin_bit_cast(bf16x2, nn), acc, false);
}
#else
#define HAVE_DOT2 0
#endif

// ---------- build phase ----------

// Two-phase per block: (1) LDS bucket histogram + out-degree, (2) reserve
// one contiguous run per bucket, direct-scatter entries. Runs are ~84
// entries (~5 lines) and single-block -> lines fill within one XCD's L2.
__global__ __launch_bounds__(256) void histscat(const int2* __restrict__ edges, int E,
                                                int* __restrict__ deg,
                                                int* __restrict__ bcnt,
                                                unsigned* __restrict__ ebuck, int NB) {
    __shared__ int hcnt[NBMAX];
    __shared__ int cursor[NBMAX];
    int tid = threadIdx.x;
    if (tid < NBMAX) hcnt[tid] = 0;
    __syncthreads();
    int base = blockIdx.x * EPB_A;
    int cnt = min(EPB_A, E - base);
    for (int i = tid; i < cnt; i += 256) {
        int2 ed = edges[base + i];
        atomicAdd(&hcnt[ed.y >> BSH], 1);
        atomicAdd(&deg[ed.x], 1);
    }
    __syncthreads();
    if (tid < NB && hcnt[tid] > 0)
        cursor[tid] = atomicAdd(&bcnt[tid], hcnt[tid]);   // reserve contiguous run
    __syncthreads();
    for (int i = tid; i < cnt; i += 256) {               // re-read (L2-warm)
        int2 ed = edges[base + i];
        int bkt = ed.y >> BSH;
        int p = atomicAdd(&cursor[bkt], 1);
        ebuck[(size_t)bkt * CAPB + p] = ((unsigned)ed.x << BSH) | (unsigned)(ed.y & (BNODES - 1));
    }
}

// fp32 -> bf16 rows pre-scaled by dinv[node]; also stores dinv.
__global__ void conv_scaled(const float4* __restrict__ xin, const int* __restrict__ deg,
                            float* __restrict__ dinv, uint4* __restrict__ xout, int n8) {
    int i = blockIdx.x * blockDim.x + threadIdx.x;
    if (i < n8) {
        int node = i >> 4;   // 16 threads x 8 dims = 128
        float dv = rsqrtf((float)(deg[node] + 1));
        if ((i & 15) == 0) dinv[node] = dv;
        float4 v0 = xin[2 * i], v1 = xin[2 * i + 1];
        uint4 o;
        o.x = packbf(dv * v0.x, dv * v0.y); o.y = packbf(dv * v0.z, dv * v0.w);
        o.z = packbf(dv * v1.x, dv * v1.y); o.w = packbf(dv * v1.z, dv * v1.w);
        xout[i] = o;
    }
}

// Exclusive scan of bucket counts -> edge_base; rowoff terminator.
__global__ __launch_bounds__(512) void scanB(const int* __restrict__ bcnt,
                                             int* __restrict__ edge_base,
                                             int* __restrict__ rowoff,
                                             int NB, int E, int N) {
    __shared__ int s[512];
    int tid = threadIdx.x;
    int val = (tid < NB) ? bcnt[tid] : 0;
    s[tid] = val;
    __syncthreads();
    for (int off = 1; off < 512; off <<= 1) {
        int t = (tid >= off) ? s[tid - off] : 0;
        __syncthreads();
        s[tid] += t;
        __syncthreads();
    }
    if (tid < NB) edge_base[tid] = s[tid] - val;
    if (tid == NB - 1) edge_base[NB] = s[tid];   // == E
    if (tid == 0) rowoff[N] = E + N;
}

// One block per bucket (1024 nodes): exact CSR segment + rowoff.
__global__ __launch_bounds__(256) void passC(const unsigned* __restrict__ ebuck,
                                             const int* __restrict__ edge_base,
                                             int* __restrict__ rowoff,
                                             int* __restrict__ csr_src, int N) {
    __shared__ int cnt[BNODES];
    __shared__ int fill[BNODES];
    __shared__ int psum[256];
    int b = blockIdx.x, tid = threadIdx.x;
    int eb0 = edge_base[b];
    int m = edge_base[b + 1] - eb0;
    const unsigned* eb = ebuck + (size_t)b * CAPB;
    for (int k = tid; k < BNODES; k += 256) cnt[k] = 0;
    __syncthreads();
    for (int i = tid; i < m; i += 256)
        atomicAdd(&cnt[eb[i] & (BNODES - 1u)], 1);
    __syncthreads();
    // 4 nodes per thread: serial prefix + block scan of per-thread sums
    int n0 = (b << BSH) + 4 * tid;
    int v[4]; int s = 0;
    #pragma unroll
    for (int j = 0; j < 4; ++j) {
        v[j] = (n0 + j < N) ? cnt[4 * tid + j] + 1 : 0;   // +1 self-loop
        s += v[j];
    }
    psum[tid] = s;
    __syncthreads();
    for (int off = 1; off < 256; off <<= 1) {
        int t = (tid >= off) ? psum[tid - off] : 0;
        __syncthreads();
        psum[tid] += t;
        __syncthreads();
    }
    int run = psum[tid] - s;          // exclusive within bucket
    int csrb = eb0 + (b << BSH);      // edges before + self-loops before (prev buckets full)
    #pragma unroll
    for (int j = 0; j < 4; ++j) {
        int node = n0 + j;
        int idx = 4 * tid + j;
        if (node < N) rowoff[node] = csrb + run;
        fill[idx] = run;
        run += v[j];
    }
    __syncthreads();
    for (int i = tid; i < m; i += 256) {
        unsigned u = eb[i];
        int p = atomicAdd(&fill[u & (BNODES - 1u)], 1);
        csr_src[csrb + p] = (int)(u >> BSH);
    }
    __syncthreads();
    #pragma unroll
    for (int j = 0; j < 4; ++j) {     // self-loop last (fill now == start + cnt)
        int node = n0 + j;
        int idx = 4 * tid + j;
        if (node < N) csr_src[csrb + fill[idx]] = node;
    }
}

// ---------- layer: 1 wave/node, 16 lanes x 16B, 4 groups, 4-deep row pipeline ----

#define SEL_LO 0x05040100u
#define SEL_HI 0x07060302u
#define NN11   0x3F803F80u   // bf16 (1.0, 1.0)

#define ACC8ADD(c)                                      \
    a0 += bf_lo(c.x); a1 += bf_hi(c.x);                 \
    a2 += bf_lo(c.y); a3 += bf_hi(c.y);                 \
    a4 += bf_lo(c.z); a5 += bf_hi(c.z);                 \
    a6 += bf_lo(c.w); a7 += bf_hi(c.w);

#if HAVE_DOT2
#define ACCPAIR(cA, cB)                                                   \
    a0 = dot2bf(__builtin_amdgcn_perm(cB.x, cA.x, SEL_LO), NN11, a0);     \
    a1 = dot2bf(__builtin_amdgcn_perm(cB.x, cA.x, SEL_HI), NN11, a1);     \
    a2 = dot2bf(__builtin_amdgcn_perm(cB.y, cA.y, SEL_LO), NN11, a2);     \
    a3 = dot2bf(__builtin_amdgcn_perm(cB.y, cA.y, SEL_HI), NN11, a3);     \
    a4 = dot2bf(__builtin_amdgcn_perm(cB.z, cA.z, SEL_LO), NN11, a4);     \
    a5 = dot2bf(__builtin_amdgcn_perm(cB.z, cA.z, SEL_HI), NN11, a5);     \
    a6 = dot2bf(__builtin_amdgcn_perm(cB.w, cA.w, SEL_LO), NN11, a6);     \
    a7 = dot2bf(__builtin_amdgcn_perm(cB.w, cA.w, SEL_HI), NN11, a7);
#else
#define ACCPAIR(cA, cB) { ACC8ADD(cA); ACC8ADD(cB); }
#endif

__global__ __launch_bounds__(256) void gcn_layer(
    const uint4* __restrict__ yin, const int* __restrict__ rowoff,
    const int* __restrict__ csr_src, const float* __restrict__ dinv,
    const float* __restrict__ w, const float* __restrict__ bia,
    void* __restrict__ xout, int N, int mode) {
    int node = blockIdx.x * 4 + (threadIdx.x >> 6);
    if (node >= N) return;
    int lane = threadIdx.x & 63;
    int h  = lane >> 4;   // 4 concurrent edge groups
    int ln = lane & 15;   // 16 lanes x uint4(16B) = 256B row
    int start = rowoff[node], end = rowoff[node + 1];
    float a0=0,a1=0,a2=0,a3=0,a4=0,a5=0,a6=0,a7=0;

    int base = start + h;            // this group's edges: base + 4*j
    int mm = end - base;
    int m = (mm > 0) ? ((mm + 3) >> 2) : 0;   // edges this group handles
    int Q = m >> 2;                  // full quads (4 edges each)
    uint4 r0, r1, r2, r3;
    int s0n = 0, s1n = 0, s2n = 0, s3n = 0;
    if (Q > 0) {
        int i0 = csr_src[base], i1 = csr_src[base + 4];
        int i2 = csr_src[base + 8], i3 = csr_src[base + 12];
        r0 = yin[(size_t)i0 * 16 + ln];
        r1 = yin[(size_t)i1 * 16 + ln];
        r2 = yin[(size_t)i2 * 16 + ln];
        r3 = yin[(size_t)i3 * 16 + ln];
        if (Q > 1) {
            s0n = csr_src[base + 16]; s1n = csr_src[base + 20];
            s2n = csr_src[base + 24]; s3n = csr_src[base + 28];
        }
    }
    for (int q = 0; q < Q; ++q) {
        uint4 c0 = r0, c1 = r1, c2 = r2, c3 = r3;
        if (q + 1 < Q) {
            r0 = yin[(size_t)s0n * 16 + ln];
            r1 = yin[(size_t)s1n * 16 + ln];
            r2 = yin[(size_t)s2n * 16 + ln];
            r3 = yin[(size_t)s3n * 16 + ln];
            if (q + 2 < Q) {
                int o = base + 16 * (q + 2);
                s0n = csr_src[o]; s1n = csr_src[o + 4];
                s2n = csr_src[o + 8]; s3n = csr_src[o + 12];
            }
        }
        ACCPAIR(c0, c1);
        ACCPAIR(c2, c3);
    }
    for (int t = 0; t < (m & 3); ++t) {
        int s = csr_src[base + 16 * Q + 4 * t];
        uint4 c = yin[(size_t)s * 16 + ln];
        ACC8ADD(c);
    }

    float dn = dinv[node];
    a0+=__shfl_xor(a0,16); a1+=__shfl_xor(a1,16); a2+=__shfl_xor(a2,16); a3+=__shfl_xor(a3,16);
    a4+=__shfl_xor(a4,16); a5+=__shfl_xor(a5,16); a6+=__shfl_xor(a6,16); a7+=__shfl_xor(a7,16);
    a0+=__shfl_xor(a0,32); a1+=__shfl_xor(a1,32); a2+=__shfl_xor(a2,32); a3+=__shfl_xor(a3,32);
    a4+=__shfl_xor(a4,32); a5+=__shfl_xor(a5,32); a6+=__shfl_xor(a6,32); a7+=__shfl_xor(a7,32);

    if (h == 0) {
        float4 w0 = ((const float4*)w)[ln * 2],   w1 = ((const float4*)w)[ln * 2 + 1];
        float4 b0 = ((const float4*)bia)[ln * 2], b1 = ((const float4*)bia)[ln * 2 + 1];
        float o0 = fmaf(a0, dn * w0.x, b0.x), o1 = fmaf(a1, dn * w0.y, b0.y);
        float o2 = fmaf(a2, dn * w0.z, b0.z), o3 = fmaf(a3, dn * w0.w, b0.w);
        float o4 = fmaf(a4, dn * w1.x, b1.x), o5 = fmaf(a5, dn * w1.y, b1.y);
        float o6 = fmaf(a6, dn * w1.z, b1.z), o7 = fmaf(a7, dn * w1.w, b1.w);
        if (mode) {   // relu, pre-scale by dinv for next layer, bf16 out
            o0 = dn * fmaxf(o0, 0.f); o1 = dn * fmaxf(o1, 0.f);
            o2 = dn * fmaxf(o2, 0.f); o3 = dn * fmaxf(o3, 0.f);
            o4 = dn * fmaxf(o4, 0.f); o5 = dn * fmaxf(o5, 0.f);
            o6 = dn * fmaxf(o6, 0.f); o7 = dn * fmaxf(o7, 0.f);
            uint4 ov;
            ov.x = packbf(o0, o1); ov.y = packbf(o2, o3);
            ov.z = packbf(o4, o5); ov.w = packbf(o6, o7);
            ((uint4*)xout)[(size_t)node * 16 + ln] = ov;
        } else {      // fp32 out
            ((float4*)xout)[(size_t)node * 32 + ln * 2]     = make_float4(o0, o1, o2, o3);
            ((float4*)xout)[(size_t)node * 32 + ln * 2 + 1] = make_float4(o4, o5, o6, o7);
        }
    }
}

// ---------- launch ----------

static inline size_t align256(size_t x) { return (x + 255) & ~(size_t)255; }

extern "C" void kernel_launch(void* const* d_in, const int* in_sizes, int n_in,
                              void* d_out, int out_size, void* d_ws, size_t ws_size,
                              hipStream_t stream) {
    const int2*  edges = (const int2*)d_in[0];
    const float* x     = (const float*)d_in[1];
    const float* w1    = (const float*)d_in[2];
    const float* b1    = (const float*)d_in[3];
    const float* w2    = (const float*)d_in[4];
    const float* b2    = (const float*)d_in[5];
    float* out = (float*)d_out;

    const int E = in_sizes[0] / 2;
    const int N = in_sizes[1] / DIM;
    const int TOT = E + N;
    const int NB   = (N + BNODES - 1) >> BSH;   // 1024-node dst buckets
    const int nblk = (E + EPB_A - 1) / EPB_A;   // histscat blocks

    // workspace carve-up
    char* p = (char*)d_ws;
    int*      deg       = (int*)p;       // N, zeroed
    int*      bcnt      = deg + N;       // NB, zeroed (contiguous with deg)
    p += align256(((size_t)N + NB) * 4);
    float*    dinv      = (float*)p;     p += align256((size_t)N * 4);
    int*      edge_base = (int*)p;       p += align256((size_t)(NB + 1) * 4);
    int*      rowoff    = (int*)p;       p += align256((size_t)(N + 1) * 4);
    unsigned* ebuck     = (unsigned*)p;  p += align256((size_t)NB * CAPB * 4);
    int*      csr_src   = (int*)p;       p += align256((size_t)TOT * 4);
    uint4*    yb        = (uint4*)p;     p += align256((size_t)N * DIM * 2);
    uint4*    hb        = (uint4*)p;     p += align256((size_t)N * DIM * 2);

    const int TPB = 256;
    int n8  = N * DIM / 8;
    int nbC = (n8 + TPB - 1) / TPB;

    hipMemsetAsync(deg, 0, ((size_t)N + NB) * 4, stream);
    histscat<<<nblk, TPB, 0, stream>>>(edges, E, deg, bcnt, ebuck, NB);
    conv_scaled<<<nbC, TPB, 0, stream>>>((const float4*)x, deg, dinv, yb, n8);
    scanB<<<1, 512, 0, stream>>>(bcnt, edge_base, rowoff, NB, E, N);
    passC<<<NB, TPB, 0, stream>>>(ebuck, edge_base, rowoff, csr_src, N);

    int nbL = (N + 3) / 4;
    gcn_layer<<<nbL, TPB, 0, stream>>>(yb, rowoff, csr_src, dinv, w1, b1, hb, N, 1);
    gcn_layer<<<nbL, TPB, 0, stream>>>(hb, rowoff, csr_src, dinv, w2, b2, out, N, 0);
}

// Round 8
// 247.370 us; speedup vs baseline: 1.1211x; 1.1211x over previous
//
#include <hip/hip_runtime.h>

#define DIM 128
#define EPB_A 8192    // edges per histscat block
#define BSH 10        // bucket = id >> 10 (1024 nodes per bucket)
#define BNODES 1024
#define CAPB 18432    // per-bucket slab capacity (mean 16384, +16 sigma)
#define NBMAX 128

// ---------- bf16 helpers ----------
__device__ __forceinline__ float bf_lo(unsigned u) { return __uint_as_float(u << 16); }
__device__ __forceinline__ float bf_hi(unsigned u) { return __uint_as_float(u & 0xffff0000u); }
__device__ __forceinline__ unsigned short f2bf(float f) {
    unsigned u = __float_as_uint(f);
    u += 0x7fff + ((u >> 16) & 1);   // round-to-nearest-even
    return (unsigned short)(u >> 16);
}
__device__ __forceinline__ unsigned packbf(float a, float b) {
    return (unsigned)f2bf(a) | ((unsigned)f2bf(b) << 16);
}

#if __has_builtin(__builtin_amdgcn_fdot2_f32_bf16)
#define HAVE_DOT2 1
typedef __bf16 bf16x2 __attribute__((ext_vector_type(2)));
__device__ __forceinline__ float dot2bf(unsigned ab, unsigned nn, float acc) {
    return __builtin_amdgcn_fdot2_f32_bf16(
        __builtin_bit_cast(bf16x2, ab), __builtin_bit_cast(bf16x2, nn), acc, false);
}
#else
#define HAVE_DOT2 0
#endif

// ---------- build phase ----------

// Two-phase per block; NO per-node global atomics. Phase 1: LDS histograms
// by dst-bucket and src-bucket. Phase 2: reserve contiguous runs in both
// slabs (one global atomic per non-empty bucket per block), then scatter
// CSR entries (4B, dst slab) and src_local counts payload (2B, src slab).
__global__ __launch_bounds__(256) void histscat(const int2* __restrict__ edges, int E,
                                                int* __restrict__ bcnt,
                                                int* __restrict__ scnt,
                                                unsigned* __restrict__ ebuck,
                                                unsigned short* __restrict__ sbuck,
                                                int NB) {
    __shared__ int hdst[NBMAX], hsrc[NBMAX], cdst[NBMAX], csrc[NBMAX];
    int tid = threadIdx.x;
    if (tid < NBMAX) { hdst[tid] = 0; hsrc[tid] = 0; }
    __syncthreads();
    int base = blockIdx.x * EPB_A;
    int cnt = min(EPB_A, E - base);
    for (int i = tid; i < cnt; i += 256) {
        int2 ed = edges[base + i];
        atomicAdd(&hdst[ed.y >> BSH], 1);
        atomicAdd(&hsrc[ed.x >> BSH], 1);
    }
    __syncthreads();
    if (tid < NB) {
        if (hdst[tid] > 0) cdst[tid] = atomicAdd(&bcnt[tid], hdst[tid]);
        if (hsrc[tid] > 0) csrc[tid] = atomicAdd(&scnt[tid], hsrc[tid]);
    }
    __syncthreads();
    for (int i = tid; i < cnt; i += 256) {   // re-read edges (L2/L3-warm)
        int2 ed = edges[base + i];
        int bd = ed.y >> BSH, bs = ed.x >> BSH;
        int p = atomicAdd(&cdst[bd], 1);
        ebuck[(size_t)bd * CAPB + p] = ((unsigned)ed.x << BSH) | (unsigned)(ed.y & (BNODES - 1));
        int q = atomicAdd(&csrc[bs], 1);
        sbuck[(size_t)bs * CAPB + q] = (unsigned short)(ed.x & (BNODES - 1));
    }
}

// One block per src-bucket: LDS-count out-degrees, write dinv coalesced.
__global__ __launch_bounds__(256) void passD(const unsigned short* __restrict__ sbuck,
                                             const int* __restrict__ scnt,
                                             float* __restrict__ dinv, int N) {
    __shared__ int cnt[BNODES];
    int b = blockIdx.x, tid = threadIdx.x;
    int m = scnt[b];
    const unsigned short* sb = sbuck + (size_t)b * CAPB;
    for (int k = tid; k < BNODES; k += 256) cnt[k] = 0;
    __syncthreads();
    for (int i = tid; i < m; i += 256) atomicAdd(&cnt[sb[i]], 1);
    __syncthreads();
    int n0 = b << BSH;
    for (int k = tid; k < BNODES; k += 256) {
        int node = n0 + k;
        if (node < N) dinv[node] = rsqrtf((float)(cnt[k] + 1));   // +1 self-loop
    }
}

// fp32 -> bf16 rows pre-scaled by dinv[node].
__global__ void conv_scaled(const float4* __restrict__ xin, const float* __restrict__ dinv,
                            uint4* __restrict__ xout, int n8) {
    int i = blockIdx.x * blockDim.x + threadIdx.x;
    if (i < n8) {
        int node = i >> 4;   // 16 threads x 8 dims = 128
        float dv = dinv[node];
        float4 v0 = xin[2 * i], v1 = xin[2 * i + 1];
        uint4 o;
        o.x = packbf(dv * v0.x, dv * v0.y); o.y = packbf(dv * v0.z, dv * v0.w);
        o.z = packbf(dv * v1.x, dv * v1.y); o.w = packbf(dv * v1.z, dv * v1.w);
        xout[i] = o;
    }
}

// Exclusive scan of dst-bucket counts -> edge_base; rowoff terminator.
__global__ __launch_bounds__(512) void scanB(const int* __restrict__ bcnt,
                                             int* __restrict__ edge_base,
                                             int* __restrict__ rowoff,
                                             int NB, int E, int N) {
    __shared__ int s[512];
    int tid = threadIdx.x;
    int val = (tid < NB) ? bcnt[tid] : 0;
    s[tid] = val;
    __syncthreads();
    for (int off = 1; off < 512; off <<= 1) {
        int t = (tid >= off) ? s[tid - off] : 0;
        __syncthreads();
        s[tid] += t;
        __syncthreads();
    }
    if (tid < NB) edge_base[tid] = s[tid] - val;
    if (tid == NB - 1) edge_base[NB] = s[tid];   // == E
    if (tid == 0) rowoff[N] = E + N;
}

// One block per dst-bucket (1024 nodes): exact CSR segment + rowoff.
__global__ __launch_bounds__(256) void passC(const unsigned* __restrict__ ebuck,
                                             const int* __restrict__ edge_base,
                                             int* __restrict__ rowoff,
                                             int* __restrict__ csr_src, int N) {
    __shared__ int cnt[BNODES];
    __shared__ int fill[BNODES];
    __shared__ int psum[256];
    int b = blockIdx.x, tid = threadIdx.x;
    int eb0 = edge_base[b];
    int m = edge_base[b + 1] - eb0;
    const unsigned* eb = ebuck + (size_t)b * CAPB;
    for (int k = tid; k < BNODES; k += 256) cnt[k] = 0;
    __syncthreads();
    for (int i = tid; i < m; i += 256)
        atomicAdd(&cnt[eb[i] & (BNODES - 1u)], 1);
    __syncthreads();
    int n0 = (b << BSH) + 4 * tid;
    int v[4]; int s = 0;
    #pragma unroll
    for (int j = 0; j < 4; ++j) {
        v[j] = (n0 + j < N) ? cnt[4 * tid + j] + 1 : 0;   // +1 self-loop
        s += v[j];
    }
    psum[tid] = s;
    __syncthreads();
    for (int off = 1; off < 256; off <<= 1) {
        int t = (tid >= off) ? psum[tid - off] : 0;
        __syncthreads();
        psum[tid] += t;
        __syncthreads();
    }
    int run = psum[tid] - s;          // exclusive within bucket
    int csrb = eb0 + (b << BSH);      // edges before + self-loops before
    #pragma unroll
    for (int j = 0; j < 4; ++j) {
        int node = n0 + j;
        int idx = 4 * tid + j;
        if (node < N) rowoff[node] = csrb + run;
        fill[idx] = run;
        run += v[j];
    }
    __syncthreads();
    for (int i = tid; i < m; i += 256) {
        unsigned u = eb[i];
        int p = atomicAdd(&fill[u & (BNODES - 1u)], 1);
        csr_src[csrb + p] = (int)(u >> BSH);
    }
    __syncthreads();
    #pragma unroll
    for (int j = 0; j < 4; ++j) {     // self-loop last (fill == start + cnt)
        int node = n0 + j;
        int idx = 4 * tid + j;
        if (node < N) csr_src[csrb + fill[idx]] = node;
    }
}

// ---------- layer: 1 wave/node, 16 lanes x 16B, 4 groups, 4-deep row pipeline ----

#define SEL_LO 0x05040100u
#define SEL_HI 0x07060302u
#define NN11   0x3F803F80u   // bf16 (1.0, 1.0)

#define ACC8ADD(c)                                      \
    a0 += bf_lo(c.x); a1 += bf_hi(c.x);                 \
    a2 += bf_lo(c.y); a3 += bf_hi(c.y);                 \
    a4 += bf_lo(c.z); a5 += bf_hi(c.z);                 \
    a6 += bf_lo(c.w); a7 += bf_hi(c.w);

#if HAVE_DOT2
#define ACCPAIR(cA, cB)                                                   \
    a0 = dot2bf(__builtin_amdgcn_perm(cB.x, cA.x, SEL_LO), NN11, a0);     \
    a1 = dot2bf(__builtin_amdgcn_perm(cB.x, cA.x, SEL_HI), NN11, a1);     \
    a2 = dot2bf(__builtin_amdgcn_perm(cB.y, cA.y, SEL_LO), NN11, a2);     \
    a3 = dot2bf(__builtin_amdgcn_perm(cB.y, cA.y, SEL_HI), NN11, a3);     \
    a4 = dot2bf(__builtin_amdgcn_perm(cB.z, cA.z, SEL_LO), NN11, a4);     \
    a5 = dot2bf(__builtin_amdgcn_perm(cB.z, cA.z, SEL_HI), NN11, a5);     \
    a6 = dot2bf(__builtin_amdgcn_perm(cB.w, cA.w, SEL_LO), NN11, a6);     \
    a7 = dot2bf(__builtin_amdgcn_perm(cB.w, cA.w, SEL_HI), NN11, a7);
#else
#define ACCPAIR(cA, cB) { ACC8ADD(cA); ACC8ADD(cB); }
#endif

__global__ __launch_bounds__(256) void gcn_layer(
    const uint4* __restrict__ yin, const int* __restrict__ rowoff,
    const int* __restrict__ csr_src, const float* __restrict__ dinv,
    const float* __restrict__ w, const float* __restrict__ bia,
    void* __restrict__ xout, int N, int mode) {
    int node = blockIdx.x * 4 + (threadIdx.x >> 6);
    if (node >= N) return;
    int lane = threadIdx.x & 63;
    int h  = lane >> 4;   // 4 concurrent edge groups
    int ln = lane & 15;   // 16 lanes x uint4(16B) = 256B row
    int start = rowoff[node], end = rowoff[node + 1];
    float a0=0,a1=0,a2=0,a3=0,a4=0,a5=0,a6=0,a7=0;

    int base = start + h;            // this group's edges: base + 4*j
    int mm = end - base;
    int m = (mm > 0) ? ((mm + 3) >> 2) : 0;   // edges this group handles
    int Q = m >> 2;                  // full quads
    uint4 r0, r1, r2, r3;
    int s0n = 0, s1n = 0, s2n = 0, s3n = 0;
    if (Q > 0) {
        int i0 = csr_src[base], i1 = csr_src[base + 4];
        int i2 = csr_src[base + 8], i3 = csr_src[base + 12];
        r0 = yin[(size_t)i0 * 16 + ln];
        r1 = yin[(size_t)i1 * 16 + ln];
        r2 = yin[(size_t)i2 * 16 + ln];
        r3 = yin[(size_t)i3 * 16 + ln];
        if (Q > 1) {
            s0n = csr_src[base + 16]; s1n = csr_src[base + 20];
            s2n = csr_src[base + 24]; s3n = csr_src[base + 28];
        }
    }
    for (int q = 0; q < Q; ++q) {
        uint4 c0 = r0, c1 = r1, c2 = r2, c3 = r3;
        if (q + 1 < Q) {
            r0 = yin[(size_t)s0n * 16 + ln];
            r1 = yin[(size_t)s1n * 16 + ln];
            r2 = yin[(size_t)s2n * 16 + ln];
            r3 = yin[(size_t)s3n * 16 + ln];
            if (q + 2 < Q) {
                int o = base + 16 * (q + 2);
                s0n = csr_src[o]; s1n = csr_src[o + 4];
                s2n = csr_src[o + 8]; s3n = csr_src[o + 12];
            }
        }
        ACCPAIR(c0, c1);
        ACCPAIR(c2, c3);
    }
    for (int t = 0; t < (m & 3); ++t) {
        int s = csr_src[base + 16 * Q + 4 * t];
        uint4 c = yin[(size_t)s * 16 + ln];
        ACC8ADD(c);
    }

    float dn = dinv[node];
    a0+=__shfl_xor(a0,16); a1+=__shfl_xor(a1,16); a2+=__shfl_xor(a2,16); a3+=__shfl_xor(a3,16);
    a4+=__shfl_xor(a4,16); a5+=__shfl_xor(a5,16); a6+=__shfl_xor(a6,16); a7+=__shfl_xor(a7,16);
    a0+=__shfl_xor(a0,32); a1+=__shfl_xor(a1,32); a2+=__shfl_xor(a2,32); a3+=__shfl_xor(a3,32);
    a4+=__shfl_xor(a4,32); a5+=__shfl_xor(a5,32); a6+=__shfl_xor(a6,32); a7+=__shfl_xor(a7,32);

    if (h == 0) {
        float4 w0 = ((const float4*)w)[ln * 2],   w1 = ((const float4*)w)[ln * 2 + 1];
        float4 b0 = ((const float4*)bia)[ln * 2], b1 = ((const float4*)bia)[ln * 2 + 1];
        float o0 = fmaf(a0, dn * w0.x, b0.x), o1 = fmaf(a1, dn * w0.y, b0.y);
        float o2 = fmaf(a2, dn * w0.z, b0.z), o3 = fmaf(a3, dn * w0.w, b0.w);
        float o4 = fmaf(a4, dn * w1.x, b1.x), o5 = fmaf(a5, dn * w1.y, b1.y);
        float o6 = fmaf(a6, dn * w1.z, b1.z), o7 = fmaf(a7, dn * w1.w, b1.w);
        if (mode) {   // relu, pre-scale by dinv for next layer, bf16 out
            o0 = dn * fmaxf(o0, 0.f); o1 = dn * fmaxf(o1, 0.f);
            o2 = dn * fmaxf(o2, 0.f); o3 = dn * fmaxf(o3, 0.f);
            o4 = dn * fmaxf(o4, 0.f); o5 = dn * fmaxf(o5, 0.f);
            o6 = dn * fmaxf(o6, 0.f); o7 = dn * fmaxf(o7, 0.f);
            uint4 ov;
            ov.x = packbf(o0, o1); ov.y = packbf(o2, o3);
            ov.z = packbf(o4, o5); ov.w = packbf(o6, o7);
            ((uint4*)xout)[(size_t)node * 16 + ln] = ov;
        } else {      // fp32 out
            ((float4*)xout)[(size_t)node * 32 + ln * 2]     = make_float4(o0, o1, o2, o3);
            ((float4*)xout)[(size_t)node * 32 + ln * 2 + 1] = make_float4(o4, o5, o6, o7);
        }
    }
}

// ---------- launch ----------

static inline size_t align256(size_t x) { return (x + 255) & ~(size_t)255; }

extern "C" void kernel_launch(void* const* d_in, const int* in_sizes, int n_in,
                              void* d_out, int out_size, void* d_ws, size_t ws_size,
                              hipStream_t stream) {
    const int2*  edges = (const int2*)d_in[0];
    const float* x     = (const float*)d_in[1];
    const float* w1    = (const float*)d_in[2];
    const float* b1    = (const float*)d_in[3];
    const float* w2    = (const float*)d_in[4];
    const float* b2    = (const float*)d_in[5];
    float* out = (float*)d_out;

    const int E = in_sizes[0] / 2;
    const int N = in_sizes[1] / DIM;
    const int TOT = E + N;
    const int NB   = (N + BNODES - 1) >> BSH;   // 1024-node buckets
    const int nblk = (E + EPB_A - 1) / EPB_A;   // histscat blocks

    // workspace carve-up
    char* p = (char*)d_ws;
    int*            bcnt      = (int*)p;             // NB, zeroed
    int*            scnt      = bcnt + NB;           // NB, zeroed (contiguous)
    p += align256((size_t)2 * NB * 4);
    float*          dinv      = (float*)p;           p += align256((size_t)N * 4);
    int*            edge_base = (int*)p;             p += align256((size_t)(NB + 1) * 4);
    int*            rowoff    = (int*)p;             p += align256((size_t)(N + 1) * 4);
    unsigned*       ebuck     = (unsigned*)p;        p += align256((size_t)NB * CAPB * 4);
    unsigned short* sbuck     = (unsigned short*)p;  p += align256((size_t)NB * CAPB * 2);
    int*            csr_src   = (int*)p;             p += align256((size_t)TOT * 4);
    uint4*          yb        = (uint4*)p;           p += align256((size_t)N * DIM * 2);
    uint4*          hb        = (uint4*)p;           p += align256((size_t)N * DIM * 2);

    const int TPB = 256;
    int n8  = N * DIM / 8;
    int nbC = (n8 + TPB - 1) / TPB;

    hipMemsetAsync(bcnt, 0, (size_t)2 * NB * 4, stream);
    histscat<<<nblk, TPB, 0, stream>>>(edges, E, bcnt, scnt, ebuck, sbuck, NB);
    passD<<<NB, TPB, 0, stream>>>(sbuck, scnt, dinv, N);
    conv_scaled<<<nbC, TPB, 0, stream>>>((const float4*)x, dinv, yb, n8);
    scanB<<<1, 512, 0, stream>>>(bcnt, edge_base, rowoff, NB, E, N);
    passC<<<NB, TPB, 0, stream>>>(ebuck, edge_base, rowoff, csr_src, N);

    int nbL = (N + 3) / 4;
    gcn_layer<<<nbL, TPB, 0, stream>>>(yb, rowoff, csr_src, dinv, w1, b1, hb, N, 1);
    gcn_layer<<<nbL, TPB, 0, stream>>>(hb, rowoff, csr_src, dinv, w2, b2, out, N, 0);
}

// Round 9
// 229.924 us; speedup vs baseline: 1.2062x; 1.0759x over previous
//
#include <hip/hip_runtime.h>

#define DIM 128
#define EPB_A 8192    // edges per histscat block
#define BSH 10        // bucket = id >> 10 (1024 nodes per bucket)
#define BNODES 1024
#define CAPB 18432    // per-bucket slab capacity (mean 16384, +16 sigma)
#define NBMAX 128

// ---------- u8 -> f32 helpers ----------
#if __has_builtin(__builtin_amdgcn_cvt_f32_ubyte0)
#define CVTU0 __builtin_amdgcn_cvt_f32_ubyte0
#define CVTU1 __builtin_amdgcn_cvt_f32_ubyte1
#define CVTU2 __builtin_amdgcn_cvt_f32_ubyte2
#define CVTU3 __builtin_amdgcn_cvt_f32_ubyte3
#else
__device__ __forceinline__ float CVTU0(unsigned u) { return (float)(u & 0xffu); }
__device__ __forceinline__ float CVTU1(unsigned u) { return (float)((u >> 8) & 0xffu); }
__device__ __forceinline__ float CVTU2(unsigned u) { return (float)((u >> 16) & 0xffu); }
__device__ __forceinline__ float CVTU3(unsigned u) { return (float)((u >> 24) & 0xffu); }
#endif

// ---------- build phase ----------

// Two-phase per block; no per-node global atomics. Phase 1: LDS histograms
// by dst-bucket and src-bucket. Phase 2: reserve contiguous runs in both
// slabs (one global atomic per non-empty bucket per block), then scatter
// CSR entries (4B, dst slab) and src_local payload (2B, src slab).
__global__ __launch_bounds__(256) void histscat(const int2* __restrict__ edges, int E,
                                                int* __restrict__ bcnt,
                                                int* __restrict__ scnt,
                                                unsigned* __restrict__ ebuck,
                                                unsigned short* __restrict__ sbuck,
                                                int NB) {
    __shared__ int hdst[NBMAX], hsrc[NBMAX], cdst[NBMAX], csrc[NBMAX];
    int tid = threadIdx.x;
    if (tid < NBMAX) { hdst[tid] = 0; hsrc[tid] = 0; }
    __syncthreads();
    int base = blockIdx.x * EPB_A;
    int cnt = min(EPB_A, E - base);
    for (int i = tid; i < cnt; i += 256) {
        int2 ed = edges[base + i];
        atomicAdd(&hdst[ed.y >> BSH], 1);
        atomicAdd(&hsrc[ed.x >> BSH], 1);
    }
    __syncthreads();
    if (tid < NB) {
        if (hdst[tid] > 0) cdst[tid] = atomicAdd(&bcnt[tid], hdst[tid]);
        if (hsrc[tid] > 0) csrc[tid] = atomicAdd(&scnt[tid], hsrc[tid]);
    }
    __syncthreads();
    for (int i = tid; i < cnt; i += 256) {   // re-read edges (L2/L3-warm)
        int2 ed = edges[base + i];
        int bd = ed.y >> BSH, bs = ed.x >> BSH;
        int p = atomicAdd(&cdst[bd], 1);
        ebuck[(size_t)bd * CAPB + p] = ((unsigned)ed.x << BSH) | (unsigned)(ed.y & (BNODES - 1));
        int q = atomicAdd(&csrc[bs], 1);
        sbuck[(size_t)bs * CAPB + q] = (unsigned short)(ed.x & (BNODES - 1));
    }
}

// One block per src-bucket: LDS-count out-degrees, write dinv coalesced.
__global__ __launch_bounds__(256) void passD(const unsigned short* __restrict__ sbuck,
                                             const int* __restrict__ scnt,
                                             float* __restrict__ dinv, int N) {
    __shared__ int cnt[BNODES];
    int b = blockIdx.x, tid = threadIdx.x;
    int m = scnt[b];
    const unsigned short* sb = sbuck + (size_t)b * CAPB;
    for (int k = tid; k < BNODES; k += 256) cnt[k] = 0;
    __syncthreads();
    for (int i = tid; i < m; i += 256) atomicAdd(&cnt[sb[i]], 1);
    __syncthreads();
    int n0 = b << BSH;
    for (int k = tid; k < BNODES; k += 256) {
        int node = n0 + k;
        if (node < N) dinv[node] = rsqrtf((float)(cnt[k] + 1));   // +1 self-loop
    }
}

// fp32 -> biased uint8 rows, pre-scaled by dinv; per-row fp32 scale.
// 16 threads per node (8 dims each).
__global__ void conv_q8(const float4* __restrict__ xin, const float* __restrict__ dinv,
                        uint2* __restrict__ qx, float* __restrict__ scx, int n8) {
    int i = blockIdx.x * blockDim.x + threadIdx.x;
    if (i >= n8) return;
    int node = i >> 4, ln = i & 15;
    float dv = dinv[node];
    float4 v0 = xin[2 * i], v1 = xin[2 * i + 1];
    float y0 = dv * v0.x, y1 = dv * v0.y, y2 = dv * v0.z, y3 = dv * v0.w;
    float y4 = dv * v1.x, y5 = dv * v1.y, y6 = dv * v1.z, y7 = dv * v1.w;
    float mx = fmaxf(fmaxf(fmaxf(fabsf(y0), fabsf(y1)), fmaxf(fabsf(y2), fabsf(y3))),
                     fmaxf(fmaxf(fabsf(y4), fabsf(y5)), fmaxf(fabsf(y6), fabsf(y7))));
    mx = fmaxf(mx, __shfl_xor(mx, 1));
    mx = fmaxf(mx, __shfl_xor(mx, 2));
    mx = fmaxf(mx, __shfl_xor(mx, 4));
    mx = fmaxf(mx, __shfl_xor(mx, 8));
    float inv = (mx > 0.f) ? 127.f / mx : 0.f;
    unsigned q0 = (unsigned)(__float2int_rn(y0 * inv) + 128);
    unsigned q1 = (unsigned)(__float2int_rn(y1 * inv) + 128);
    unsigned q2 = (unsigned)(__float2int_rn(y2 * inv) + 128);
    unsigned q3 = (unsigned)(__float2int_rn(y3 * inv) + 128);
    unsigned q4 = (unsigned)(__float2int_rn(y4 * inv) + 128);
    unsigned q5 = (unsigned)(__float2int_rn(y5 * inv) + 128);
    unsigned q6 = (unsigned)(__float2int_rn(y6 * inv) + 128);
    unsigned q7 = (unsigned)(__float2int_rn(y7 * inv) + 128);
    uint2 ov;
    ov.x = q0 | (q1 << 8) | (q2 << 16) | (q3 << 24);
    ov.y = q4 | (q5 << 8) | (q6 << 16) | (q7 << 24);
    qx[(size_t)node * 16 + ln] = ov;
    if (ln == 0) scx[node] = mx * (1.f / 127.f);
}

// One block per dst-bucket (1024 nodes): exact CSR segment + rowoff.
// Fused bucket-base computation (scan of bcnt) — no separate scan kernel.
__global__ __launch_bounds__(256) void passC(const unsigned* __restrict__ ebuck,
                                             const int* __restrict__ bcnt,
                                             int* __restrict__ rowoff,
                                             int* __restrict__ csr_src,
                                             int N, int E, int NB) {
    __shared__ int cnt[BNODES];
    __shared__ int fill[BNODES];
    __shared__ int psum[256];
    int b = blockIdx.x, tid = threadIdx.x;
    // eb0 = sum of bcnt[k] for k < b
    psum[tid] = (tid < NB && tid < b) ? bcnt[tid] : 0;
    __syncthreads();
    for (int off = 128; off > 0; off >>= 1) {
        if (tid < off) psum[tid] += psum[tid + off];
        __syncthreads();
    }
    int eb0 = psum[0];
    int m = bcnt[b];
    __syncthreads();
    const unsigned* eb = ebuck + (size_t)b * CAPB;
    for (int k = tid; k < BNODES; k += 256) cnt[k] = 0;
    __syncthreads();
    for (int i = tid; i < m; i += 256)
        atomicAdd(&cnt[eb[i] & (BNODES - 1u)], 1);
    __syncthreads();
    int n0 = (b << BSH) + 4 * tid;
    int v[4]; int s = 0;
    #pragma unroll
    for (int j = 0; j < 4; ++j) {
        v[j] = (n0 + j < N) ? cnt[4 * tid + j] + 1 : 0;   // +1 self-loop
        s += v[j];
    }
    psum[tid] = s;
    __syncthreads();
    for (int off = 1; off < 256; off <<= 1) {
        int t = (tid >= off) ? psum[tid - off] : 0;
        __syncthreads();
        psum[tid] += t;
        __syncthreads();
    }
    int run = psum[tid] - s;          // exclusive within bucket
    int csrb = eb0 + (b << BSH);      // edges before + self-loops before
    #pragma unroll
    for (int j = 0; j < 4; ++j) {
        int node = n0 + j;
        int idx = 4 * tid + j;
        if (node < N) rowoff[node] = csrb + run;
        fill[idx] = run;
        run += v[j];
    }
    if (b == NB - 1 && tid == 0) rowoff[N] = E + N;
    __syncthreads();
    for (int i = tid; i < m; i += 256) {
        unsigned u = eb[i];
        int p = atomicAdd(&fill[u & (BNODES - 1u)], 1);
        csr_src[csrb + p] = (int)(u >> BSH);
    }
    __syncthreads();
    #pragma unroll
    for (int j = 0; j < 4; ++j) {     // self-loop last (fill == start + cnt)
        int node = n0 + j;
        int idx = 4 * tid + j;
        if (node < N) csr_src[csrb + fill[idx]] = node;
    }
}

// ---------- layer: 1 wave/node, 16 lanes x 8B row, 4 groups, 4-deep pipeline ----
// BIASED: input rows are uint8 biased by 128 (dequant sc*(u-128) via corr term).
// LAST:   write fp32 output; else relu + dinv pre-scale + unbiased uint8 quant.

#define ACCQ(r, sc) do {                                                   \
    if (BIASED) corr += sc;                                                \
    a0 = fmaf(sc, CVTU0(r.x), a0); a1 = fmaf(sc, CVTU1(r.x), a1);          \
    a2 = fmaf(sc, CVTU2(r.x), a2); a3 = fmaf(sc, CVTU3(r.x), a3);          \
    a4 = fmaf(sc, CVTU0(r.y), a4); a5 = fmaf(sc, CVTU1(r.y), a5);          \
    a6 = fmaf(sc, CVTU2(r.y), a6); a7 = fmaf(sc, CVTU3(r.y), a7);          \
} while (0)

template<int BIASED, int LAST>
__global__ __launch_bounds__(256) void gcn_layer(
    const uint2* __restrict__ qin, const float* __restrict__ scin,
    const int* __restrict__ rowoff, const int* __restrict__ csr_src,
    const float* __restrict__ dinv,
    const float* __restrict__ w, const float* __restrict__ bia,
    void* __restrict__ qout, float* __restrict__ scout, int N) {
    int node = blockIdx.x * 4 + (threadIdx.x >> 6);
    if (node >= N) return;
    int lane = threadIdx.x & 63;
    int h  = lane >> 4;   // 4 concurrent edge groups
    int ln = lane & 15;   // 16 lanes x uint2(8B) = 128B row
    int start = rowoff[node], end = rowoff[node + 1];
    float a0=0,a1=0,a2=0,a3=0,a4=0,a5=0,a6=0,a7=0, corr=0;

    int base = start + h;            // this group's edges: base + 4*j
    int mm = end - base;
    int m = (mm > 0) ? ((mm + 3) >> 2) : 0;   // edges this group handles
    int Q = m >> 2;                  // full quads
    uint2 r0, r1, r2, r3;
    float c0f=0, c1f=0, c2f=0, c3f=0;
    int s0n = 0, s1n = 0, s2n = 0, s3n = 0;
    if (Q > 0) {
        int i0 = csr_src[base], i1 = csr_src[base + 4];
        int i2 = csr_src[base + 8], i3 = csr_src[base + 12];
        c0f = scin[i0]; c1f = scin[i1]; c2f = scin[i2]; c3f = scin[i3];
        r0 = qin[(size_t)i0 * 16 + ln];
        r1 = qin[(size_t)i1 * 16 + ln];
        r2 = qin[(size_t)i2 * 16 + ln];
        r3 = qin[(size_t)i3 * 16 + ln];
        if (Q > 1) {
            s0n = csr_src[base + 16]; s1n = csr_src[base + 20];
            s2n = csr_src[base + 24]; s3n = csr_src[base + 28];
        }
    }
    for (int q = 0; q < Q; ++q) {
        uint2 d0 = r0, d1 = r1, d2 = r2, d3 = r3;
        float e0 = c0f, e1 = c1f, e2 = c2f, e3 = c3f;
        if (q + 1 < Q) {
            c0f = scin[s0n]; c1f = scin[s1n]; c2f = scin[s2n]; c3f = scin[s3n];
            r0 = qin[(size_t)s0n * 16 + ln];
            r1 = qin[(size_t)s1n * 16 + ln];
            r2 = qin[(size_t)s2n * 16 + ln];
            r3 = qin[(size_t)s3n * 16 + ln];
            if (q + 2 < Q) {
                int o = base + 16 * (q + 2);
                s0n = csr_src[o]; s1n = csr_src[o + 4];
                s2n = csr_src[o + 8]; s3n = csr_src[o + 12];
            }
        }
        ACCQ(d0, e0); ACCQ(d1, e1); ACCQ(d2, e2); ACCQ(d3, e3);
    }
    for (int t = 0; t < (m & 3); ++t) {
        int s = csr_src[base + 16 * Q + 4 * t];
        float sc = scin[s];
        uint2 c = qin[(size_t)s * 16 + ln];
        ACCQ(c, sc);
    }

    a0+=__shfl_xor(a0,16); a1+=__shfl_xor(a1,16); a2+=__shfl_xor(a2,16); a3+=__shfl_xor(a3,16);
    a4+=__shfl_xor(a4,16); a5+=__shfl_xor(a5,16); a6+=__shfl_xor(a6,16); a7+=__shfl_xor(a7,16);
    a0+=__shfl_xor(a0,32); a1+=__shfl_xor(a1,32); a2+=__shfl_xor(a2,32); a3+=__shfl_xor(a3,32);
    a4+=__shfl_xor(a4,32); a5+=__shfl_xor(a5,32); a6+=__shfl_xor(a6,32); a7+=__shfl_xor(a7,32);
    if (BIASED) {
        corr += __shfl_xor(corr, 16);
        corr += __shfl_xor(corr, 32);
        float c = 128.f * corr;
        a0 -= c; a1 -= c; a2 -= c; a3 -= c; a4 -= c; a5 -= c; a6 -= c; a7 -= c;
    }

    if (h == 0) {
        float dn = dinv[node];
        float4 w0 = ((const float4*)w)[ln * 2],   w1 = ((const float4*)w)[ln * 2 + 1];
        float4 b0 = ((const float4*)bia)[ln * 2], b1 = ((const float4*)bia)[ln * 2 + 1];
        float o0 = fmaf(a0, dn * w0.x, b0.x), o1 = fmaf(a1, dn * w0.y, b0.y);
        float o2 = fmaf(a2, dn * w0.z, b0.z), o3 = fmaf(a3, dn * w0.w, b0.w);
        float o4 = fmaf(a4, dn * w1.x, b1.x), o5 = fmaf(a5, dn * w1.y, b1.y);
        float o6 = fmaf(a6, dn * w1.z, b1.z), o7 = fmaf(a7, dn * w1.w, b1.w);
        if (!LAST) {   // relu, pre-scale by dinv, unbiased uint8 quant for next layer
            o0 = dn * fmaxf(o0, 0.f); o1 = dn * fmaxf(o1, 0.f);
            o2 = dn * fmaxf(o2, 0.f); o3 = dn * fmaxf(o3, 0.f);
            o4 = dn * fmaxf(o4, 0.f); o5 = dn * fmaxf(o5, 0.f);
            o6 = dn * fmaxf(o6, 0.f); o7 = dn * fmaxf(o7, 0.f);
            float mx = fmaxf(fmaxf(fmaxf(o0, o1), fmaxf(o2, o3)),
                             fmaxf(fmaxf(o4, o5), fmaxf(o6, o7)));
            mx = fmaxf(mx, __shfl_xor(mx, 1));
            mx = fmaxf(mx, __shfl_xor(mx, 2));
            mx = fmaxf(mx, __shfl_xor(mx, 4));
            mx = fmaxf(mx, __shfl_xor(mx, 8));
            float inv = (mx > 0.f) ? 255.f / mx : 0.f;
            unsigned q0 = (unsigned)__float2int_rn(o0 * inv);
            unsigned q1 = (unsigned)__float2int_rn(o1 * inv);
            unsigned q2 = (unsigned)__float2int_rn(o2 * inv);
            unsigned q3 = (unsigned)__float2int_rn(o3 * inv);
            unsigned q4 = (unsigned)__float2int_rn(o4 * inv);
            unsigned q5 = (unsigned)__float2int_rn(o5 * inv);
            unsigned q6 = (unsigned)__float2int_rn(o6 * inv);
            unsigned q7 = (unsigned)__float2int_rn(o7 * inv);
            uint2 ov;
            ov.x = q0 | (q1 << 8) | (q2 << 16) | (q3 << 24);
            ov.y = q4 | (q5 << 8) | (q6 << 16) | (q7 << 24);
            ((uint2*)qout)[(size_t)node * 16 + ln] = ov;
            if (ln == 0) scout[node] = mx * (1.f / 255.f);
        } else {       // fp32 out
            ((float4*)qout)[(size_t)node * 32 + ln * 2]     = make_float4(o0, o1, o2, o3);
            ((float4*)qout)[(size_t)node * 32 + ln * 2 + 1] = make_float4(o4, o5, o6, o7);
        }
    }
}

// ---------- launch ----------

static inline size_t align256(size_t x) { return (x + 255) & ~(size_t)255; }

extern "C" void kernel_launch(void* const* d_in, const int* in_sizes, int n_in,
                              void* d_out, int out_size, void* d_ws, size_t ws_size,
                              hipStream_t stream) {
    const int2*  edges = (const int2*)d_in[0];
    const float* x     = (const float*)d_in[1];
    const float* w1    = (const float*)d_in[2];
    const float* b1    = (const float*)d_in[3];
    const float* w2    = (const float*)d_in[4];
    const float* b2    = (const float*)d_in[5];
    float* out = (float*)d_out;

    const int E = in_sizes[0] / 2;
    const int N = in_sizes[1] / DIM;
    const int TOT = E + N;
    const int NB   = (N + BNODES - 1) >> BSH;   // 1024-node buckets
    const int nblk = (E + EPB_A - 1) / EPB_A;   // histscat blocks

    // workspace carve-up
    char* p = (char*)d_ws;
    int*            bcnt    = (int*)p;             // NB, zeroed
    int*            scnt    = bcnt + NB;           // NB, zeroed (contiguous)
    p += align256((size_t)2 * NB * 4);
    float*          dinv    = (float*)p;           p += align256((size_t)N * 4);
    float*          scX     = (float*)p;           p += align256((size_t)N * 4);
    float*          scH     = (float*)p;           p += align256((size_t)N * 4);
    int*            rowoff  = (int*)p;             p += align256((size_t)(N + 1) * 4);
    unsigned*       ebuck   = (unsigned*)p;        p += align256((size_t)NB * CAPB * 4);
    unsigned short* sbuck   = (unsigned short*)p;  p += align256((size_t)NB * CAPB * 2);
    int*            csr_src = (int*)p;             p += align256((size_t)TOT * 4);
    uint2*          qx      = (uint2*)p;           p += align256((size_t)N * DIM);
    uint2*          qh      = (uint2*)p;           p += align256((size_t)N * DIM);

    const int TPB = 256;
    int n8  = N * DIM / 8;
    int nbC = (n8 + TPB - 1) / TPB;

    hipMemsetAsync(bcnt, 0, (size_t)2 * NB * 4, stream);
    histscat<<<nblk, TPB, 0, stream>>>(edges, E, bcnt, scnt, ebuck, sbuck, NB);
    passD<<<NB, TPB, 0, stream>>>(sbuck, scnt, dinv, N);
    conv_q8<<<nbC, TPB, 0, stream>>>((const float4*)x, dinv, qx, scX, n8);
    passC<<<NB, TPB, 0, stream>>>(ebuck, bcnt, rowoff, csr_src, N, E, NB);

    int nbL = (N + 3) / 4;
    gcn_layer<1, 0><<<nbL, TPB, 0, stream>>>(qx, scX, rowoff, csr_src, dinv,
                                             w1, b1, qh, scH, N);
    gcn_layer<0, 1><<<nbL, TPB, 0, stream>>>(qh, scH, rowoff, csr_src, dinv,
                                             w2, b2, out, nullptr, N);
}

// Round 10
// 207.375 us; speedup vs baseline: 1.3373x; 1.1087x over previous
//
#include <hip/hip_runtime.h>

#define DIM 128
#define EPB_A 8192    // edges per histscat block
#define BSH 10        // bucket = id >> 10 (1024 nodes per bucket)
#define BNODES 1024
#define CAPB 18432    // per-bucket slab capacity (mean 16384, +16 sigma)
#define NBMAX 128

// ---------- u8 -> f32 helpers ----------
#if __has_builtin(__builtin_amdgcn_cvt_f32_ubyte0)
#define CVTU0 __builtin_amdgcn_cvt_f32_ubyte0
#define CVTU1 __builtin_amdgcn_cvt_f32_ubyte1
#define CVTU2 __builtin_amdgcn_cvt_f32_ubyte2
#define CVTU3 __builtin_amdgcn_cvt_f32_ubyte3
#else
__device__ __forceinline__ float CVTU0(unsigned u) { return (float)(u & 0xffu); }
__device__ __forceinline__ float CVTU1(unsigned u) { return (float)((u >> 8) & 0xffu); }
__device__ __forceinline__ float CVTU2(unsigned u) { return (float)((u >> 16) & 0xffu); }
__device__ __forceinline__ float CVTU3(unsigned u) { return (float)((u >> 24) & 0xffu); }
#endif

// ---------- build phase (unchanged from round 9) ----------

__global__ __launch_bounds__(256) void histscat(const int2* __restrict__ edges, int E,
                                                int* __restrict__ bcnt,
                                                int* __restrict__ scnt,
                                                unsigned* __restrict__ ebuck,
                                                unsigned short* __restrict__ sbuck,
                                                int NB) {
    __shared__ int hdst[NBMAX], hsrc[NBMAX], cdst[NBMAX], csrc[NBMAX];
    int tid = threadIdx.x;
    if (tid < NBMAX) { hdst[tid] = 0; hsrc[tid] = 0; }
    __syncthreads();
    int base = blockIdx.x * EPB_A;
    int cnt = min(EPB_A, E - base);
    for (int i = tid; i < cnt; i += 256) {
        int2 ed = edges[base + i];
        atomicAdd(&hdst[ed.y >> BSH], 1);
        atomicAdd(&hsrc[ed.x >> BSH], 1);
    }
    __syncthreads();
    if (tid < NB) {
        if (hdst[tid] > 0) cdst[tid] = atomicAdd(&bcnt[tid], hdst[tid]);
        if (hsrc[tid] > 0) csrc[tid] = atomicAdd(&scnt[tid], hsrc[tid]);
    }
    __syncthreads();
    for (int i = tid; i < cnt; i += 256) {   // re-read edges (L2/L3-warm)
        int2 ed = edges[base + i];
        int bd = ed.y >> BSH, bs = ed.x >> BSH;
        int p = atomicAdd(&cdst[bd], 1);
        ebuck[(size_t)bd * CAPB + p] = ((unsigned)ed.x << BSH) | (unsigned)(ed.y & (BNODES - 1));
        int q = atomicAdd(&csrc[bs], 1);
        sbuck[(size_t)bs * CAPB + q] = (unsigned short)(ed.x & (BNODES - 1));
    }
}

__global__ __launch_bounds__(256) void passD(const unsigned short* __restrict__ sbuck,
                                             const int* __restrict__ scnt,
                                             float* __restrict__ dinv, int N) {
    __shared__ int cnt[BNODES];
    int b = blockIdx.x, tid = threadIdx.x;
    int m = scnt[b];
    const unsigned short* sb = sbuck + (size_t)b * CAPB;
    for (int k = tid; k < BNODES; k += 256) cnt[k] = 0;
    __syncthreads();
    for (int i = tid; i < m; i += 256) atomicAdd(&cnt[sb[i]], 1);
    __syncthreads();
    int n0 = b << BSH;
    for (int k = tid; k < BNODES; k += 256) {
        int node = n0 + k;
        if (node < N) dinv[node] = rsqrtf((float)(cnt[k] + 1));   // +1 self-loop
    }
}

__global__ void conv_q8(const float4* __restrict__ xin, const float* __restrict__ dinv,
                        uint2* __restrict__ qx, float* __restrict__ scx, int n8) {
    int i = blockIdx.x * blockDim.x + threadIdx.x;
    if (i >= n8) return;
    int node = i >> 4, ln = i & 15;
    float dv = dinv[node];
    float4 v0 = xin[2 * i], v1 = xin[2 * i + 1];
    float y0 = dv * v0.x, y1 = dv * v0.y, y2 = dv * v0.z, y3 = dv * v0.w;
    float y4 = dv * v1.x, y5 = dv * v1.y, y6 = dv * v1.z, y7 = dv * v1.w;
    float mx = fmaxf(fmaxf(fmaxf(fabsf(y0), fabsf(y1)), fmaxf(fabsf(y2), fabsf(y3))),
                     fmaxf(fmaxf(fabsf(y4), fabsf(y5)), fmaxf(fabsf(y6), fabsf(y7))));
    mx = fmaxf(mx, __shfl_xor(mx, 1));
    mx = fmaxf(mx, __shfl_xor(mx, 2));
    mx = fmaxf(mx, __shfl_xor(mx, 4));
    mx = fmaxf(mx, __shfl_xor(mx, 8));
    float inv = (mx > 0.f) ? 127.f / mx : 0.f;
    unsigned q0 = (unsigned)(__float2int_rn(y0 * inv) + 128);
    unsigned q1 = (unsigned)(__float2int_rn(y1 * inv) + 128);
    unsigned q2 = (unsigned)(__float2int_rn(y2 * inv) + 128);
    unsigned q3 = (unsigned)(__float2int_rn(y3 * inv) + 128);
    unsigned q4 = (unsigned)(__float2int_rn(y4 * inv) + 128);
    unsigned q5 = (unsigned)(__float2int_rn(y5 * inv) + 128);
    unsigned q6 = (unsigned)(__float2int_rn(y6 * inv) + 128);
    unsigned q7 = (unsigned)(__float2int_rn(y7 * inv) + 128);
    uint2 ov;
    ov.x = q0 | (q1 << 8) | (q2 << 16) | (q3 << 24);
    ov.y = q4 | (q5 << 8) | (q6 << 16) | (q7 << 24);
    qx[(size_t)node * 16 + ln] = ov;
    if (ln == 0) scx[node] = mx * (1.f / 127.f);
}

__global__ __launch_bounds__(256) void passC(const unsigned* __restrict__ ebuck,
                                             const int* __restrict__ bcnt,
                                             int* __restrict__ rowoff,
                                             int* __restrict__ csr_src,
                                             int N, int E, int NB) {
    __shared__ int cnt[BNODES];
    __shared__ int fill[BNODES];
    __shared__ int psum[256];
    int b = blockIdx.x, tid = threadIdx.x;
    psum[tid] = (tid < NB && tid < b) ? bcnt[tid] : 0;
    __syncthreads();
    for (int off = 128; off > 0; off >>= 1) {
        if (tid < off) psum[tid] += psum[tid + off];
        __syncthreads();
    }
    int eb0 = psum[0];
    int m = bcnt[b];
    __syncthreads();
    const unsigned* eb = ebuck + (size_t)b * CAPB;
    for (int k = tid; k < BNODES; k += 256) cnt[k] = 0;
    __syncthreads();
    for (int i = tid; i < m; i += 256)
        atomicAdd(&cnt[eb[i] & (BNODES - 1u)], 1);
    __syncthreads();
    int n0 = (b << BSH) + 4 * tid;
    int v[4]; int s = 0;
    #pragma unroll
    for (int j = 0; j < 4; ++j) {
        v[j] = (n0 + j < N) ? cnt[4 * tid + j] + 1 : 0;   // +1 self-loop
        s += v[j];
    }
    psum[tid] = s;
    __syncthreads();
    for (int off = 1; off < 256; off <<= 1) {
        int t = (tid >= off) ? psum[tid - off] : 0;
        __syncthreads();
        psum[tid] += t;
        __syncthreads();
    }
    int run = psum[tid] - s;
    int csrb = eb0 + (b << BSH);
    #pragma unroll
    for (int j = 0; j < 4; ++j) {
        int node = n0 + j;
        int idx = 4 * tid + j;
        if (node < N) rowoff[node] = csrb + run;
        fill[idx] = run;
        run += v[j];
    }
    if (b == NB - 1 && tid == 0) rowoff[N] = E + N;
    __syncthreads();
    for (int i = tid; i < m; i += 256) {
        unsigned u = eb[i];
        int p = atomicAdd(&fill[u & (BNODES - 1u)], 1);
        csr_src[csrb + p] = (int)(u >> BSH);
    }
    __syncthreads();
    #pragma unroll
    for (int j = 0; j < 4; ++j) {
        int node = n0 + j;
        int idx = 4 * tid + j;
        if (node < N) csr_src[csrb + fill[idx]] = node;
    }
}

// ---------- layer: breadth-first gather pipeline ----------
// Per wave: 1 coalesced 64-int csr load + 1 64-lane scale gather, then up to
// 16 row loads per group issued back-to-back (no dependent hops between them).

#define ACCQ(r, sc) do {                                                   \
    a0 = fmaf(sc, CVTU0(r.x), a0); a1 = fmaf(sc, CVTU1(r.x), a1);          \
    a2 = fmaf(sc, CVTU2(r.x), a2); a3 = fmaf(sc, CVTU3(r.x), a3);          \
    a4 = fmaf(sc, CVTU0(r.y), a4); a5 = fmaf(sc, CVTU1(r.y), a5);          \
    a6 = fmaf(sc, CVTU2(r.y), a6); a7 = fmaf(sc, CVTU3(r.y), a7);          \
} while (0)

template<int BIASED, int LAST>
__global__ __launch_bounds__(256) void gcn_layer(
    const uint2* __restrict__ qin, const float* __restrict__ scin,
    const int* __restrict__ rowoff, const int* __restrict__ csr_src,
    const float* __restrict__ dinv,
    const float* __restrict__ w, const float* __restrict__ bia,
    void* __restrict__ qout, float* __restrict__ scout, int N) {
    int node = blockIdx.x * 4 + (threadIdx.x >> 6);
    if (node >= N) return;
    int lane = threadIdx.x & 63;
    int h  = lane >> 4;        // 4 concurrent edge groups
    int ln = lane & 15;        // 16 lanes x uint2(8B) = 128B row
    int gb = lane & 48;        // first lane of this group (for shfl)
    int start = rowoff[node], end = rowoff[node + 1];
    float a0=0,a1=0,a2=0,a3=0,a4=0,a5=0,a6=0,a7=0;

    int base = start + h;                    // group's edges: base + 4*j
    int mm = end - base;
    int m = (mm > 0) ? ((mm + 3) >> 2) : 0;  // edges this group handles
    int j16 = min(m, 16);

    // breadth-first metadata preload: lane ln holds edge j=ln of its group.
    // csr addresses start + h + 4*ln cover start..start+63 across the wave
    // -> one fully-coalesced load; then one 64-lane random scale gather.
    int  msrc = 0;
    float msc = 0.f;
    if (ln < j16) {
        msrc = csr_src[base + 4 * ln];
        msc  = scin[msrc];
    }

    const char* qbase = (const char*)qin + (ln << 3);

    // issue up to 16 row loads back-to-back (shfl puts src on the addr path,
    // no memory dependency between loads), then consume in order.
    uint2 rb[16];
    #pragma unroll
    for (int j = 0; j < 16; ++j) {
        if (j < j16) {
            int sj = __shfl(msrc, gb + j);
            rb[j] = *(const uint2*)(qbase + (((unsigned)sj) << 7));
        }
    }
    #pragma unroll
    for (int j = 0; j < 16; ++j) {
        if (j < j16) {
            float sc = __shfl(msc, gb + j);
            ACCQ(rb[j], sc);
        }
    }

    // rare tail (deg > 64): dependent loads, original style
    float corr_t = 0.f;
    for (int j = 16; j < m; ++j) {
        int s = csr_src[base + 4 * j];
        float sc = scin[s];
        uint2 c = *(const uint2*)(qbase + (((unsigned)s) << 7));
        ACCQ(c, sc);
        if (BIASED && ln == 0) corr_t += sc;
    }

    a0+=__shfl_xor(a0,16); a1+=__shfl_xor(a1,16); a2+=__shfl_xor(a2,16); a3+=__shfl_xor(a3,16);
    a4+=__shfl_xor(a4,16); a5+=__shfl_xor(a5,16); a6+=__shfl_xor(a6,16); a7+=__shfl_xor(a7,16);
    a0+=__shfl_xor(a0,32); a1+=__shfl_xor(a1,32); a2+=__shfl_xor(a2,32); a3+=__shfl_xor(a3,32);
    a4+=__shfl_xor(a4,32); a5+=__shfl_xor(a5,32); a6+=__shfl_xor(a6,32); a7+=__shfl_xor(a7,32);

    if (BIASED) {
        // corr = sum of all edges' scales: each preloaded lane holds one
        // edge's scale exactly once; tail counted once (ln==0 lanes).
        float cv = msc + corr_t;
        cv += __shfl_xor(cv, 1);  cv += __shfl_xor(cv, 2);
        cv += __shfl_xor(cv, 4);  cv += __shfl_xor(cv, 8);
        cv += __shfl_xor(cv, 16); cv += __shfl_xor(cv, 32);
        float c = 128.f * cv;
        a0 -= c; a1 -= c; a2 -= c; a3 -= c; a4 -= c; a5 -= c; a6 -= c; a7 -= c;
    }

    if (h == 0) {
        float dn = dinv[node];
        float4 w0 = ((const float4*)w)[ln * 2],   w1 = ((const float4*)w)[ln * 2 + 1];
        float4 b0 = ((const float4*)bia)[ln * 2], b1 = ((const float4*)bia)[ln * 2 + 1];
        float o0 = fmaf(a0, dn * w0.x, b0.x), o1 = fmaf(a1, dn * w0.y, b0.y);
        float o2 = fmaf(a2, dn * w0.z, b0.z), o3 = fmaf(a3, dn * w0.w, b0.w);
        float o4 = fmaf(a4, dn * w1.x, b1.x), o5 = fmaf(a5, dn * w1.y, b1.y);
        float o6 = fmaf(a6, dn * w1.z, b1.z), o7 = fmaf(a7, dn * w1.w, b1.w);
        if (!LAST) {   // relu, pre-scale by dinv, unbiased uint8 quant for next layer
            o0 = dn * fmaxf(o0, 0.f); o1 = dn * fmaxf(o1, 0.f);
            o2 = dn * fmaxf(o2, 0.f); o3 = dn * fmaxf(o3, 0.f);
            o4 = dn * fmaxf(o4, 0.f); o5 = dn * fmaxf(o5, 0.f);
            o6 = dn * fmaxf(o6, 0.f); o7 = dn * fmaxf(o7, 0.f);
            float mx = fmaxf(fmaxf(fmaxf(o0, o1), fmaxf(o2, o3)),
                             fmaxf(fmaxf(o4, o5), fmaxf(o6, o7)));
            mx = fmaxf(mx, __shfl_xor(mx, 1));
            mx = fmaxf(mx, __shfl_xor(mx, 2));
            mx = fmaxf(mx, __shfl_xor(mx, 4));
            mx = fmaxf(mx, __shfl_xor(mx, 8));
            float inv = (mx > 0.f) ? 255.f / mx : 0.f;
            unsigned q0 = (unsigned)__float2int_rn(o0 * inv);
            unsigned q1 = (unsigned)__float2int_rn(o1 * inv);
            unsigned q2 = (unsigned)__float2int_rn(o2 * inv);
            unsigned q3 = (unsigned)__float2int_rn(o3 * inv);
            unsigned q4 = (unsigned)__float2int_rn(o4 * inv);
            unsigned q5 = (unsigned)__float2int_rn(o5 * inv);
            unsigned q6 = (unsigned)__float2int_rn(o6 * inv);
            unsigned q7 = (unsigned)__float2int_rn(o7 * inv);
            uint2 ov;
            ov.x = q0 | (q1 << 8) | (q2 << 16) | (q3 << 24);
            ov.y = q4 | (q5 << 8) | (q6 << 16) | (q7 << 24);
            ((uint2*)qout)[(size_t)node * 16 + ln] = ov;
            if (ln == 0) scout[node] = mx * (1.f / 255.f);
        } else {       // fp32 out
            ((float4*)qout)[(size_t)node * 32 + ln * 2]     = make_float4(o0, o1, o2, o3);
            ((float4*)qout)[(size_t)node * 32 + ln * 2 + 1] = make_float4(o4, o5, o6, o7);
        }
    }
}

// ---------- launch ----------

static inline size_t align256(size_t x) { return (x + 255) & ~(size_t)255; }

extern "C" void kernel_launch(void* const* d_in, const int* in_sizes, int n_in,
                              void* d_out, int out_size, void* d_ws, size_t ws_size,
                              hipStream_t stream) {
    const int2*  edges = (const int2*)d_in[0];
    const float* x     = (const float*)d_in[1];
    const float* w1    = (const float*)d_in[2];
    const float* b1    = (const float*)d_in[3];
    const float* w2    = (const float*)d_in[4];
    const float* b2    = (const float*)d_in[5];
    float* out = (float*)d_out;

    const int E = in_sizes[0] / 2;
    const int N = in_sizes[1] / DIM;
    const int TOT = E + N;
    const int NB   = (N + BNODES - 1) >> BSH;   // 1024-node buckets
    const int nblk = (E + EPB_A - 1) / EPB_A;   // histscat blocks

    // workspace carve-up
    char* p = (char*)d_ws;
    int*            bcnt    = (int*)p;             // NB, zeroed
    int*            scnt    = bcnt + NB;           // NB, zeroed (contiguous)
    p += align256((size_t)2 * NB * 4);
    float*          dinv    = (float*)p;           p += align256((size_t)N * 4);
    float*          scX     = (float*)p;           p += align256((size_t)N * 4);
    float*          scH     = (float*)p;           p += align256((size_t)N * 4);
    int*            rowoff  = (int*)p;             p += align256((size_t)(N + 1) * 4);
    unsigned*       ebuck   = (unsigned*)p;        p += align256((size_t)NB * CAPB * 4);
    unsigned short* sbuck   = (unsigned short*)p;  p += align256((size_t)NB * CAPB * 2);
    int*            csr_src = (int*)p;             p += align256((size_t)TOT * 4);
    uint2*          qx      = (uint2*)p;           p += align256((size_t)N * DIM);
    uint2*          qh      = (uint2*)p;           p += align256((size_t)N * DIM);

    const int TPB = 256;
    int n8  = N * DIM / 8;
    int nbC = (n8 + TPB - 1) / TPB;

    hipMemsetAsync(bcnt, 0, (size_t)2 * NB * 4, stream);
    histscat<<<nblk, TPB, 0, stream>>>(edges, E, bcnt, scnt, ebuck, sbuck, NB);
    passD<<<NB, TPB, 0, stream>>>(sbuck, scnt, dinv, N);
    conv_q8<<<nbC, TPB, 0, stream>>>((const float4*)x, dinv, qx, scX, n8);
    passC<<<NB, TPB, 0, stream>>>(ebuck, bcnt, rowoff, csr_src, N, E, NB);

    int nbL = (N + 3) / 4;
    gcn_layer<1, 0><<<nbL, TPB, 0, stream>>>(qx, scX, rowoff, csr_src, dinv,
                                             w1, b1, qh, scH, N);
    gcn_layer<0, 1><<<nbL, TPB, 0, stream>>>(qh, scH, rowoff, csr_src, dinv,
                                             w2, b2, out, nullptr, N);
}

// Round 11
// 166.522 us; speedup vs baseline: 1.6654x; 1.2453x over previous
//
#include <hip/hip_runtime.h>

#define DIM 128
#define EPB_A 8192    // edges per histscat block
#define BSH 10        // bucket = id >> 10 (1024 nodes per bucket)
#define BNODES 1024
#define CAPB 18432    // per-bucket slab capacity (mean 16384, +16 sigma)
#define NBMAX 128

// ---------- u8 -> f32 helpers ----------
#if __has_builtin(__builtin_amdgcn_cvt_f32_ubyte0)
#define CVTU0 __builtin_amdgcn_cvt_f32_ubyte0
#define CVTU1 __builtin_amdgcn_cvt_f32_ubyte1
#define CVTU2 __builtin_amdgcn_cvt_f32_ubyte2
#define CVTU3 __builtin_amdgcn_cvt_f32_ubyte3
#else
__device__ __forceinline__ float CVTU0(unsigned u) { return (float)(u & 0xffu); }
__device__ __forceinline__ float CVTU1(unsigned u) { return (float)((u >> 8) & 0xffu); }
__device__ __forceinline__ float CVTU2(unsigned u) { return (float)((u >> 16) & 0xffu); }
__device__ __forceinline__ float CVTU3(unsigned u) { return (float)((u >> 24) & 0xffu); }
#endif

// ---------- build phase ----------

// 512 threads, single global read: 16 edges/thread staged in registers,
// LDS dual histogram, per-bucket run reservation, scatter from registers.
__global__ __launch_bounds__(512) void histscat(const int2* __restrict__ edges, int E,
                                                int* __restrict__ bcnt,
                                                int* __restrict__ scnt,
                                                unsigned* __restrict__ ebuck,
                                                unsigned short* __restrict__ sbuck,
                                                int NB) {
    __shared__ int hdst[NBMAX], hsrc[NBMAX], cdst[NBMAX], csrc[NBMAX];
    int tid = threadIdx.x;
    if (tid < NBMAX) { hdst[tid] = 0; hsrc[tid] = 0; }
    __syncthreads();
    int base = blockIdx.x * EPB_A;
    int cnt = min(EPB_A, E - base);
    int2 ed[16];
    #pragma unroll
    for (int i = 0; i < 16; ++i) {
        int idx = tid + i * 512;
        ed[i] = (idx < cnt) ? edges[base + idx] : make_int2(-1, -1);
    }
    #pragma unroll
    for (int i = 0; i < 16; ++i) {
        if (ed[i].x >= 0) {
            atomicAdd(&hdst[ed[i].y >> BSH], 1);
            atomicAdd(&hsrc[ed[i].x >> BSH], 1);
        }
    }
    __syncthreads();
    if (tid < NB) {
        if (hdst[tid] > 0) cdst[tid] = atomicAdd(&bcnt[tid], hdst[tid]);
        if (hsrc[tid] > 0) csrc[tid] = atomicAdd(&scnt[tid], hsrc[tid]);
    }
    __syncthreads();
    #pragma unroll
    for (int i = 0; i < 16; ++i) {
        if (ed[i].x >= 0) {
            int bd = ed[i].y >> BSH, bs = ed[i].x >> BSH;
            int p = atomicAdd(&cdst[bd], 1);
            ebuck[(size_t)bd * CAPB + p] =
                ((unsigned)ed[i].x << BSH) | (unsigned)(ed[i].y & (BNODES - 1));
            int q = atomicAdd(&csrc[bs], 1);
            sbuck[(size_t)bs * CAPB + q] = (unsigned short)(ed[i].x & (BNODES - 1));
        }
    }
}

// One block (1024 thr) per src-bucket: count out-degrees, write dinv.
__global__ __launch_bounds__(1024) void passD(const unsigned short* __restrict__ sbuck,
                                              const int* __restrict__ scnt,
                                              float* __restrict__ dinv, int N) {
    __shared__ int cnt[BNODES];
    int b = blockIdx.x, tid = threadIdx.x;
    int m = scnt[b];
    const unsigned short* sb = sbuck + (size_t)b * CAPB;
    cnt[tid] = 0;
    __syncthreads();
    for (int i = tid; i < m; i += 1024) atomicAdd(&cnt[sb[i]], 1);
    __syncthreads();
    int node = (b << BSH) + tid;
    if (node < N) dinv[node] = rsqrtf((float)(cnt[tid] + 1));   // +1 self-loop
}

__global__ void conv_q8(const float4* __restrict__ xin, const float* __restrict__ dinv,
                        uint2* __restrict__ qx, float* __restrict__ scx, int n8) {
    int i = blockIdx.x * blockDim.x + threadIdx.x;
    if (i >= n8) return;
    int node = i >> 4, ln = i & 15;
    float dv = dinv[node];
    float4 v0 = xin[2 * i], v1 = xin[2 * i + 1];
    float y0 = dv * v0.x, y1 = dv * v0.y, y2 = dv * v0.z, y3 = dv * v0.w;
    float y4 = dv * v1.x, y5 = dv * v1.y, y6 = dv * v1.z, y7 = dv * v1.w;
    float mx = fmaxf(fmaxf(fmaxf(fabsf(y0), fabsf(y1)), fmaxf(fabsf(y2), fabsf(y3))),
                     fmaxf(fmaxf(fabsf(y4), fabsf(y5)), fmaxf(fabsf(y6), fabsf(y7))));
    mx = fmaxf(mx, __shfl_xor(mx, 1));
    mx = fmaxf(mx, __shfl_xor(mx, 2));
    mx = fmaxf(mx, __shfl_xor(mx, 4));
    mx = fmaxf(mx, __shfl_xor(mx, 8));
    float inv = (mx > 0.f) ? 127.f / mx : 0.f;
    unsigned q0 = (unsigned)(__float2int_rn(y0 * inv) + 128);
    unsigned q1 = (unsigned)(__float2int_rn(y1 * inv) + 128);
    unsigned q2 = (unsigned)(__float2int_rn(y2 * inv) + 128);
    unsigned q3 = (unsigned)(__float2int_rn(y3 * inv) + 128);
    unsigned q4 = (unsigned)(__float2int_rn(y4 * inv) + 128);
    unsigned q5 = (unsigned)(__float2int_rn(y5 * inv) + 128);
    unsigned q6 = (unsigned)(__float2int_rn(y6 * inv) + 128);
    unsigned q7 = (unsigned)(__float2int_rn(y7 * inv) + 128);
    uint2 ov;
    ov.x = q0 | (q1 << 8) | (q2 << 16) | (q3 << 24);
    ov.y = q4 | (q5 << 8) | (q6 << 16) | (q7 << 24);
    qx[(size_t)node * 16 + ln] = ov;
    if (ln == 0) scx[node] = mx * (1.f / 127.f);
}

// One block (1024 thr) per dst-bucket: exact CSR segment + rowoff.
__global__ __launch_bounds__(1024) void passC(const unsigned* __restrict__ ebuck,
                                              const int* __restrict__ bcnt,
                                              int* __restrict__ rowoff,
                                              int* __restrict__ csr_src,
                                              int N, int E, int NB) {
    __shared__ int cnt[BNODES];
    __shared__ int fill[BNODES];
    __shared__ int s[BNODES];
    __shared__ int red[128];
    int b = blockIdx.x, tid = threadIdx.x;
    // eb0 = sum of bcnt[k] for k < b
    if (tid < 128) red[tid] = (tid < NB && tid < b) ? bcnt[tid] : 0;
    __syncthreads();
    for (int off = 64; off > 0; off >>= 1) {
        if (tid < off) red[tid] += red[tid + off];
        __syncthreads();
    }
    int eb0 = red[0];
    int m = bcnt[b];
    const unsigned* eb = ebuck + (size_t)b * CAPB;
    cnt[tid] = 0;
    __syncthreads();
    for (int i = tid; i < m; i += 1024)
        atomicAdd(&cnt[eb[i] & (BNODES - 1u)], 1);
    __syncthreads();
    int node = (b << BSH) + tid;
    int val = (node < N) ? cnt[tid] + 1 : 0;   // +1 self-loop
    s[tid] = val;
    __syncthreads();
    for (int off = 1; off < 1024; off <<= 1) {
        int t = (tid >= off) ? s[tid - off] : 0;
        __syncthreads();
        s[tid] += t;
        __syncthreads();
    }
    int excl = s[tid] - val;
    int csrb = eb0 + (b << BSH);
    if (node < N) rowoff[node] = csrb + excl;
    fill[tid] = excl;
    if (b == NB - 1 && tid == 0) rowoff[N] = E + N;
    __syncthreads();
    for (int i = tid; i < m; i += 1024) {
        unsigned u = eb[i];
        int p = atomicAdd(&fill[u & (BNODES - 1u)], 1);
        csr_src[csrb + p] = (int)(u >> BSH);
    }
    __syncthreads();
    if (node < N) csr_src[csrb + fill[tid]] = node;   // self-loop last
}

// ---------- layer: guard-free batched gather ----------
// Wave = 1 node. 4 groups x 16 lanes x 8B. Lane L preloads edge offset L
// (coalesced csr + one scale gather); slots are UNCONDITIONAL: out-of-range
// lanes get clamped index + zero scale, so row loads batch with no branches.

#define ACCQ(r, sc) do {                                                   \
    a0 = fmaf(sc, CVTU0(r.x), a0); a1 = fmaf(sc, CVTU1(r.x), a1);          \
    a2 = fmaf(sc, CVTU2(r.x), a2); a3 = fmaf(sc, CVTU3(r.x), a3);          \
    a4 = fmaf(sc, CVTU0(r.y), a4); a5 = fmaf(sc, CVTU1(r.y), a5);          \
    a6 = fmaf(sc, CVTU2(r.y), a6); a7 = fmaf(sc, CVTU3(r.y), a7);          \
} while (0)

#define SLOT(j) do {                                                       \
    int  sj = __shfl(msrc, gb + (j));                                      \
    float sc = __shfl(msc, gb + (j));                                      \
    uint2 r = *(const uint2*)(qbase + (((unsigned)sj) << 7));              \
    ACCQ(r, sc);                                                           \
} while (0)

template<int BIASED, int LAST>
__global__ __launch_bounds__(256) void gcn_layer(
    const uint2* __restrict__ qin, const float* __restrict__ scin,
    const int* __restrict__ rowoff, const int* __restrict__ csr_src,
    const float* __restrict__ dinv,
    const float* __restrict__ w, const float* __restrict__ bia,
    void* __restrict__ qout, float* __restrict__ scout, int N) {
    int node = blockIdx.x * 4 + (threadIdx.x >> 6);
    if (node >= N) return;
    node = __builtin_amdgcn_readfirstlane(node);
    int lane = threadIdx.x & 63;
    int h  = lane >> 4;        // group (4 concurrent edges)
    int ln = lane & 15;        // 16 lanes x uint2(8B) = 128B row
    int gb = lane & 48;        // first lane of this group
    int start = rowoff[node];
    int mm = rowoff[node + 1] - start;     // row degree incl self-loop (>=1)
    float a0=0,a1=0,a2=0,a3=0,a4=0,a5=0,a6=0,a7=0;

    // preload: lane L holds edge offset L (group L>>4... covers 0..63 via
    // start + h + 4*ln == start + interleave; bijective & coalesced)
    int off = h + 4 * ln;                  // this lane's preloaded edge offset
    int offc = min(off, mm - 1);
    int  msrc = csr_src[start + offc];
    float msc = (off < mm) ? scin[msrc] : 0.f;

    const char* qbase = (const char*)qin + (ln << 3);

    // main slots: group h consumes offsets h+4j; slot j's data is on lane gb+j
    SLOT(0); SLOT(1); SLOT(2); SLOT(3); SLOT(4); SLOT(5);
    if (__any(mm > 24)) {                  // extended slots (deg > 24), ~3% of waves
        SLOT(6); SLOT(7); SLOT(8); SLOT(9); SLOT(10);
        SLOT(11); SLOT(12); SLOT(13); SLOT(14); SLOT(15);
    }
    // ultra tail (deg > 64): dependent loads
    float corr_t = 0.f;
    for (int o = 64 + h; o < mm; o += 4) {
        int sx = csr_src[start + o];
        float sc = scin[sx];
        uint2 c = *(const uint2*)(qbase + (((unsigned)sx) << 7));
        ACCQ(c, sc);
        if (BIASED && ln == 0) corr_t += sc;
    }

    a0+=__shfl_xor(a0,16); a1+=__shfl_xor(a1,16); a2+=__shfl_xor(a2,16); a3+=__shfl_xor(a3,16);
    a4+=__shfl_xor(a4,16); a5+=__shfl_xor(a5,16); a6+=__shfl_xor(a6,16); a7+=__shfl_xor(a7,16);
    a0+=__shfl_xor(a0,32); a1+=__shfl_xor(a1,32); a2+=__shfl_xor(a2,32); a3+=__shfl_xor(a3,32);
    a4+=__shfl_xor(a4,32); a5+=__shfl_xor(a5,32); a6+=__shfl_xor(a6,32); a7+=__shfl_xor(a7,32);

    if (BIASED) {
        // each in-range preloaded lane holds one edge's scale exactly once
        float cv = msc + corr_t;
        cv += __shfl_xor(cv, 1);  cv += __shfl_xor(cv, 2);
        cv += __shfl_xor(cv, 4);  cv += __shfl_xor(cv, 8);
        cv += __shfl_xor(cv, 16); cv += __shfl_xor(cv, 32);
        float c = 128.f * cv;
        a0 -= c; a1 -= c; a2 -= c; a3 -= c; a4 -= c; a5 -= c; a6 -= c; a7 -= c;
    }

    if (h == 0) {
        float dn = dinv[node];
        float4 w0 = ((const float4*)w)[ln * 2],   w1 = ((const float4*)w)[ln * 2 + 1];
        float4 b0 = ((const float4*)bia)[ln * 2], b1 = ((const float4*)bia)[ln * 2 + 1];
        float o0 = fmaf(a0, dn * w0.x, b0.x), o1 = fmaf(a1, dn * w0.y, b0.y);
        float o2 = fmaf(a2, dn * w0.z, b0.z), o3 = fmaf(a3, dn * w0.w, b0.w);
        float o4 = fmaf(a4, dn * w1.x, b1.x), o5 = fmaf(a5, dn * w1.y, b1.y);
        float o6 = fmaf(a6, dn * w1.z, b1.z), o7 = fmaf(a7, dn * w1.w, b1.w);
        if (!LAST) {   // relu, pre-scale by dinv, unbiased uint8 quant for next layer
            o0 = dn * fmaxf(o0, 0.f); o1 = dn * fmaxf(o1, 0.f);
            o2 = dn * fmaxf(o2, 0.f); o3 = dn * fmaxf(o3, 0.f);
            o4 = dn * fmaxf(o4, 0.f); o5 = dn * fmaxf(o5, 0.f);
            o6 = dn * fmaxf(o6, 0.f); o7 = dn * fmaxf(o7, 0.f);
            float mx = fmaxf(fmaxf(fmaxf(o0, o1), fmaxf(o2, o3)),
                             fmaxf(fmaxf(o4, o5), fmaxf(o6, o7)));
            mx = fmaxf(mx, __shfl_xor(mx, 1));
            mx = fmaxf(mx, __shfl_xor(mx, 2));
            mx = fmaxf(mx, __shfl_xor(mx, 4));
            mx = fmaxf(mx, __shfl_xor(mx, 8));
            float inv = (mx > 0.f) ? 255.f / mx : 0.f;
            unsigned q0 = (unsigned)__float2int_rn(o0 * inv);
            unsigned q1 = (unsigned)__float2int_rn(o1 * inv);
            unsigned q2 = (unsigned)__float2int_rn(o2 * inv);
            unsigned q3 = (unsigned)__float2int_rn(o3 * inv);
            unsigned q4 = (unsigned)__float2int_rn(o4 * inv);
            unsigned q5 = (unsigned)__float2int_rn(o5 * inv);
            unsigned q6 = (unsigned)__float2int_rn(o6 * inv);
            unsigned q7 = (unsigned)__float2int_rn(o7 * inv);
            uint2 ov;
            ov.x = q0 | (q1 << 8) | (q2 << 16) | (q3 << 24);
            ov.y = q4 | (q5 << 8) | (q6 << 16) | (q7 << 24);
            ((uint2*)qout)[(size_t)node * 16 + ln] = ov;
            if (ln == 0) scout[node] = mx * (1.f / 255.f);
        } else {       // fp32 out
            ((float4*)qout)[(size_t)node * 32 + ln * 2]     = make_float4(o0, o1, o2, o3);
            ((float4*)qout)[(size_t)node * 32 + ln * 2 + 1] = make_float4(o4, o5, o6, o7);
        }
    }
}

// ---------- launch ----------

static inline size_t align256(size_t x) { return (x + 255) & ~(size_t)255; }

extern "C" void kernel_launch(void* const* d_in, const int* in_sizes, int n_in,
                              void* d_out, int out_size, void* d_ws, size_t ws_size,
                              hipStream_t stream) {
    const int2*  edges = (const int2*)d_in[0];
    const float* x     = (const float*)d_in[1];
    const float* w1    = (const float*)d_in[2];
    const float* b1    = (const float*)d_in[3];
    const float* w2    = (const float*)d_in[4];
    const float* b2    = (const float*)d_in[5];
    float* out = (float*)d_out;

    const int E = in_sizes[0] / 2;
    const int N = in_sizes[1] / DIM;
    const int TOT = E + N;
    const int NB   = (N + BNODES - 1) >> BSH;   // 1024-node buckets
    const int nblk = (E + EPB_A - 1) / EPB_A;   // histscat blocks

    // workspace carve-up
    char* p = (char*)d_ws;
    int*            bcnt    = (int*)p;             // NB, zeroed
    int*            scnt    = bcnt + NB;           // NB, zeroed (contiguous)
    p += align256((size_t)2 * NB * 4);
    float*          dinv    = (float*)p;           p += align256((size_t)N * 4);
    float*          scX     = (float*)p;           p += align256((size_t)N * 4);
    float*          scH     = (float*)p;           p += align256((size_t)N * 4);
    int*            rowoff  = (int*)p;             p += align256((size_t)(N + 1) * 4);
    unsigned*       ebuck   = (unsigned*)p;        p += align256((size_t)NB * CAPB * 4);
    unsigned short* sbuck   = (unsigned short*)p;  p += align256((size_t)NB * CAPB * 2);
    int*            csr_src = (int*)p;             p += align256((size_t)TOT * 4);
    uint2*          qx      = (uint2*)p;           p += align256((size_t)N * DIM);
    uint2*          qh      = (uint2*)p;           p += align256((size_t)N * DIM);

    const int TPB = 256;
    int n8  = N * DIM / 8;
    int nbC = (n8 + TPB - 1) / TPB;

    hipMemsetAsync(bcnt, 0, (size_t)2 * NB * 4, stream);
    histscat<<<nblk, 512, 0, stream>>>(edges, E, bcnt, scnt, ebuck, sbuck, NB);
    passD<<<NB, 1024, 0, stream>>>(sbuck, scnt, dinv, N);
    conv_q8<<<nbC, TPB, 0, stream>>>((const float4*)x, dinv, qx, scX, n8);
    passC<<<NB, 1024, 0, stream>>>(ebuck, bcnt, rowoff, csr_src, N, E, NB);

    int nbL = (N + 3) / 4;
    gcn_layer<1, 0><<<nbL, TPB, 0, stream>>>(qx, scX, rowoff, csr_src, dinv,
                                             w1, b1, qh, scH, N);
    gcn_layer<0, 1><<<nbL, TPB, 0, stream>>>(qh, scH, rowoff, csr_src, dinv,
                                             w2, b2, out, nullptr, N);
}